// Round 12
// baseline (449.205 us; speedup 1.0000x reference)
//
#include <hip/hip_runtime.h>
#include <hip/hip_bf16.h>
#include <cstdint>
#include <cstddef>

#define NNODES 50000

using s8v = __attribute__((ext_vector_type(8))) short;
using f4v = __attribute__((ext_vector_type(4))) float;

__device__ __forceinline__ unsigned short f2bf(float f) {
  union { float f; uint32_t u; } x; x.f = f;
  uint32_t r = x.u + 0x7FFF + ((x.u >> 16) & 1);  // RNE
  return (unsigned short)(r >> 16);
}
__device__ __forceinline__ float bf2f(unsigned short b) {
  union { uint32_t u; float f; } x; x.u = ((uint32_t)b) << 16;
  return x.f;
}
// order-preserving float<->uint keys for atomicMax
__device__ __forceinline__ unsigned fkey(float f) {
  unsigned u = __float_as_uint(f);
  return u ^ (((int)u >> 31) | 0x80000000u);
}
__device__ __forceinline__ float fdec(unsigned k) {
  return (k & 0x80000000u) ? __uint_as_float(k ^ 0x80000000u)
                           : __uint_as_float(~k);
}

// ---------------- CSR build ----------------

__global__ void k_deg_init(int* __restrict__ deg, unsigned* __restrict__ mk, int n) {
  int i = blockIdx.x * 256 + threadIdx.x;
  if (i < n) deg[i] = 1;  // self-loop occupies slot 0
  if (i < 8) mk[i] = 0;
}

__global__ void k_deg_count(const int* __restrict__ ei, int* __restrict__ deg,
                            int* __restrict__ rank, int E) {
  int e = blockIdx.x * 256 + threadIdx.x;
  if (e < E) rank[e] = atomicAdd(&deg[ei[E + e]], 1);
}

__global__ __launch_bounds__(256) void k_scan1(const int* __restrict__ deg,
                                               int* __restrict__ offs,
                                               int* __restrict__ blksum, int n) {
  __shared__ int part[256];
  const int tid = threadIdx.x;
  const int base = blockIdx.x * 2048 + tid * 8;
  int v[8]; int s = 0;
  #pragma unroll
  for (int u = 0; u < 8; ++u) {
    int i = base + u;
    v[u] = (i < n) ? deg[i] : 0;
    s += v[u];
  }
  part[tid] = s;
  __syncthreads();
  for (int off = 1; off < 256; off <<= 1) {
    int t = (tid >= off) ? part[tid - off] : 0;
    __syncthreads();
    part[tid] += t;
    __syncthreads();
  }
  int run = (tid == 0) ? 0 : part[tid - 1];
  #pragma unroll
  for (int u = 0; u < 8; ++u) {
    int i = base + u;
    run += v[u];
    if (i < n) offs[i + 1] = run;
  }
  if (tid == 255) blksum[blockIdx.x] = part[255];
}

__global__ void k_scan2(int* __restrict__ blksum, int nb) {
  int t = threadIdx.x;
  int v = (t < nb) ? blksum[t] : 0;
  for (int off = 1; off < 64; off <<= 1) {
    int o = __shfl_up(v, off, 64);
    if (t >= off) v += o;
  }
  if (t < nb) blksum[t] = v;
}

__global__ void k_scan3(int* __restrict__ offs, const int* __restrict__ blksum, int n) {
  int i = blockIdx.x * 256 + threadIdx.x;
  if (i < n) {
    int b = i >> 11;
    if (b > 0) offs[i + 1] += blksum[b - 1];
  }
  if (i == 0) offs[0] = 0;
}

__global__ void k_selfloop(const int* __restrict__ offs, int* __restrict__ srt, int n) {
  int i = blockIdx.x * 256 + threadIdx.x;
  if (i < n) srt[offs[i]] = i;
}

__global__ void k_scatter(const int* __restrict__ ei, const int* __restrict__ offs,
                          const int* __restrict__ rank, int* __restrict__ srt, int E) {
  int e = blockIdx.x * 256 + threadIdx.x;
  if (e < E) {
    int s = ei[e], d = ei[E + e];
    srt[offs[d] + rank[e]] = s;
  }
}

// ---------------- weight pre-transpose + bf16 convert (all 4 layers) ----------------

__global__ void k_wt_all(const float* __restrict__ W0, const float* __restrict__ R0,
                         const float* __restrict__ W1, const float* __restrict__ R1,
                         const float* __restrict__ W2, const float* __restrict__ R2,
                         const float* __restrict__ W3, const float* __restrict__ R3,
                         unsigned short* __restrict__ Wt0, unsigned short* __restrict__ Wt1,
                         unsigned short* __restrict__ Wt2, unsigned short* __restrict__ Wt3) {
  int idx = blockIdx.x * 256 + threadIdx.x;
  const float *W, *R; unsigned short* Wt; int K, DO, l;
  if (idx < 49152)      { l = idx;          W = W0; R = R0; Wt = Wt0; K = 256; DO = 96; }
  else if (idx < 67584) { l = idx - 49152;  W = W1; R = R1; Wt = Wt1; K = 96;  DO = 96; }
  else if (idx < 86016) { l = idx - 67584;  W = W2; R = R2; Wt = Wt2; K = 96;  DO = 96; }
  else if (idx < 95232) { l = idx - 86016;  W = W3; R = R3; Wt = Wt3; K = 96;  DO = 48; }
  else return;
  int n = l / K, k = l % K;
  float v = (n < DO) ? W[(size_t)k * DO + n] : R[(size_t)k * DO + (n - DO)];
  Wt[l] = f2bf(v);
}

// ---------------- layer-0 MFMA GEMM (standalone; R10 structure) ----------------

template<int KDIM, int NT>   // NT = DOW/16
__global__ __launch_bounds__(256) void gemm_mfma(
    const float* __restrict__ x, const unsigned short* __restrict__ Wt,
    const float* __restrict__ a_s, const float* __restrict__ a_d,
    unsigned short* __restrict__ hb, float* __restrict__ xR,
    float* __restrict__ asb, float* __restrict__ adb,
    unsigned* __restrict__ mk) {
  constexpr int DOW = NT * 16;
  constexpr int DO  = DOW / 2;
  constexpr int NH  = NT / 2;
  constexpr int BM  = 64;
  constexpr int AP  = 40;
  constexpr int NBS = (DOW * 4 + 255) / 256;
  __shared__ __align__(16) unsigned short Al[BM * AP];
  __shared__ __align__(16) unsigned short Bl[DOW * AP];
  __shared__ float wmax[4][2];

  const int tid  = threadIdx.x;
  const int wave = tid >> 6;
  const int lane = tid & 63;
  const int row0 = blockIdx.x * BM;

  const int ar = tid >> 2, ako = (tid & 3) * 8;
  const int agr = row0 + ar;

  f4v acc[NT];
  #pragma unroll
  for (int t = 0; t < NT; ++t) acc[t] = (f4v)(0.f);

  const int fr = lane & 15;
  const int fq = lane >> 4;

  auto loadA = [&](int k0) -> s8v {
    s8v out = (s8v)(0);
    if (agr < NNODES) {
      const float* xp = &x[(size_t)agr * KDIM + k0 + ako];
      float4 v0 = *(const float4*)(xp);
      float4 v1 = *(const float4*)(xp + 4);
      out[0] = (short)f2bf(v0.x); out[1] = (short)f2bf(v0.y);
      out[2] = (short)f2bf(v0.z); out[3] = (short)f2bf(v0.w);
      out[4] = (short)f2bf(v1.x); out[5] = (short)f2bf(v1.y);
      out[6] = (short)f2bf(v1.z); out[7] = (short)f2bf(v1.w);
    }
    return out;
  };

  // prologue: stage tile 0
  {
    s8v aC = loadA(0);
    s8v bC[NBS];
    #pragma unroll
    for (int i = 0; i < NBS; ++i) {
      int s = tid + i * 256;
      if (s < DOW * 4) {
        int n = s >> 2, kq = (s & 3) * 8;
        bC[i] = *(const s8v*)&Wt[(size_t)n * KDIM + kq];
      }
    }
    *(s8v*)&Al[ar * AP + ako] = aC;
    #pragma unroll
    for (int i = 0; i < NBS; ++i) {
      int s = tid + i * 256;
      if (s < DOW * 4) {
        int n = s >> 2, kq = (s & 3) * 8;
        *(s8v*)&Bl[n * AP + kq] = bC[i];
      }
    }
  }

  for (int k0 = 32; k0 <= KDIM; k0 += 32) {
    __syncthreads();
    const bool more = (k0 < KDIM);
    s8v aN; s8v bN[NBS];
    if (more) {
      aN = loadA(k0);
      #pragma unroll
      for (int i = 0; i < NBS; ++i) {
        int s = tid + i * 256;
        if (s < DOW * 4) {
          int n = s >> 2, kq = (s & 3) * 8;
          bN[i] = *(const s8v*)&Wt[(size_t)n * KDIM + k0 + kq];
        }
      }
    }
    s8v a = *(const s8v*)&Al[(wave * 16 + fr) * AP + fq * 8];
    #pragma unroll
    for (int t = 0; t < NT; ++t) {
      s8v b = *(const s8v*)&Bl[(t * 16 + fr) * AP + fq * 8];
      acc[t] = __builtin_amdgcn_mfma_f32_16x16x32_bf16(a, b, acc[t], 0, 0, 0);
    }
    if (more) {
      __syncthreads();
      *(s8v*)&Al[ar * AP + ako] = aN;
      #pragma unroll
      for (int i = 0; i < NBS; ++i) {
        int s = tid + i * 256;
        if (s < DOW * 4) {
          int n = s >> 2, kq = (s & 3) * 8;
          *(s8v*)&Bl[n * AP + kq] = bN[i];
        }
      }
    }
  }

  #pragma unroll
  for (int t = 0; t < NT; ++t) {
    int gcol = t * 16 + fr;
    #pragma unroll
    for (int r = 0; r < 4; ++r) {
      int grow = row0 + wave * 16 + fq * 4 + r;
      if (grow >= NNODES) continue;
      if (t < NH) hb[(size_t)grow * DO + gcol] = f2bf(acc[t][r]);
      else        xR[(size_t)grow * DO + (gcol - DO)] = acc[t][r];
    }
  }

  float avs[NH], avd[NH];
  #pragma unroll
  for (int t = 0; t < NH; ++t) {
    avs[t] = a_s[t * 16 + fr];
    avd[t] = a_d[t * 16 + fr];
  }
  float lms = -INFINITY, lmd = -INFINITY;
  #pragma unroll
  for (int r = 0; r < 4; ++r) {
    float ps = 0.f, pd = 0.f;
    #pragma unroll
    for (int t = 0; t < NH; ++t) {
      ps = fmaf(acc[t][r], avs[t], ps);
      pd = fmaf(acc[t][r], avd[t], pd);
    }
    #pragma unroll
    for (int off = 1; off < 16; off <<= 1) {
      ps += __shfl_xor(ps, off, 64);
      pd += __shfl_xor(pd, off, 64);
    }
    int grow = row0 + wave * 16 + fq * 4 + r;
    if (fr == 0 && grow < NNODES) { asb[grow] = ps; adb[grow] = pd; }
    lms = fmaxf(lms, ps); lmd = fmaxf(lmd, pd);
  }
  lms = fmaxf(lms, __shfl_xor(lms, 16, 64));
  lms = fmaxf(lms, __shfl_xor(lms, 32, 64));
  lmd = fmaxf(lmd, __shfl_xor(lmd, 16, 64));
  lmd = fmaxf(lmd, __shfl_xor(lmd, 32, 64));
  if (lane == 0) { wmax[wave][0] = lms; wmax[wave][1] = lmd; }
  __syncthreads();
  if (tid == 0) {
    float a = fmaxf(fmaxf(wmax[0][0], wmax[1][0]), fmaxf(wmax[2][0], wmax[3][0]));
    float b = fmaxf(fmaxf(wmax[0][1], wmax[1][1]), fmaxf(wmax[2][1], wmax[3][1]));
    atomicMax(mk + 0, fkey(a));
    atomicMax(mk + 1, fkey(b));
  }
}

// ---------------- fused aggregate(+relu+residual) + NEXT-layer GEMM ----------------
// Block = 16 nodes (4 waves x 4 nodes). Phase 1: GR-gather softmax aggregate;
// out rows -> bf16 LDS tile (or d_out when NTn==0). Phase 2 (NTn>0): 16-row MFMA
// h_next/xR_next + fused alpha dots + next-layer global max bound.

template<int DO, int NTn>   // NTn = next DOW/16 (12 or 6); 0 = final layer
__global__ __launch_bounds__(256) void k_agg_fused(
    const unsigned short* __restrict__ hb, const float* __restrict__ xRl,
    const float* __restrict__ as_, const float* __restrict__ ad_,
    const int* __restrict__ srt, const int* __restrict__ offs,
    const unsigned* __restrict__ mk,
    const unsigned short* __restrict__ Wtn,
    const float* __restrict__ nas, const float* __restrict__ nad,
    unsigned short* __restrict__ hbn, float* __restrict__ xRn,
    float* __restrict__ asbn, float* __restrict__ adbn,
    unsigned* __restrict__ mkn, float* __restrict__ dout) {
  constexpr int CAP = 256;
  constexpr int LR  = DO / 4;    // lanes per row (24 or 12)
  constexpr int GR  = 48 / LR;   // rows per gather instruction (2 or 4)
  constexpr int PIT = 104;       // xAl row pitch (ushorts)
  __shared__ float wbuf[4][CAP];
  __shared__ int   sbuf[4][CAP];
  __shared__ __align__(16) unsigned short xAl[16 * PIT];
  __shared__ float pps[4][16], ppd[4][16];
  const int lane  = threadIdx.x & 63;
  const int wid   = threadIdx.x >> 6;
  const int node0 = blockIdx.x * 16;
  const float m = fmaxf(0.f, fdec(mk[0]) + fdec(mk[1]));
  const int g    = lane / LR;
  const int pidx = lane % LR;
  const bool act = lane < 48;

  // ---- phase 1: 4 nodes per wave ----
  for (int nd = 0; nd < 4; ++nd) {
    const int row  = wid * 4 + nd;
    const int node = node0 + row;
    const int start = offs[node];
    const int deg   = offs[node + 1] - start;
    const float adn = ad_[node];

    float ssum = 0.f;
    for (int idx = lane; idx < deg; idx += 64) {
      int s = srt[start + idx];
      float v = as_[s] + adn;
      v = v > 0.f ? v : 0.2f * v;
      float w = __expf(v - m);
      if (idx < CAP) { wbuf[wid][idx] = w; sbuf[wid][idx] = s; }
      ssum += w;
    }
    #pragma unroll
    for (int off = 32; off; off >>= 1) ssum += __shfl_xor(ssum, off, 64);
    const float inv = 1.f / fmaxf(ssum, 1e-30f);

    const int dcap = min(deg, CAP);
    float ax = 0.f, ay = 0.f, az = 0.f, aw = 0.f;
    for (int base = 0; base < dcap; base += 8 * GR) {
      float wv[8]; int sv[8];
      #pragma unroll
      for (int u = 0; u < 8; ++u) {
        int e = base + u * GR + g;
        bool ok = act && (e < dcap);
        sv[u] = sbuf[wid][ok ? e : 0];
        wv[u] = ok ? wbuf[wid][e] : 0.f;
      }
      uint2 hv[8];
      #pragma unroll
      for (int u = 0; u < 8; ++u)
        hv[u] = act ? *(const uint2*)&hb[(size_t)sv[u] * DO + pidx * 4]
                    : make_uint2(0u, 0u);
      #pragma unroll
      for (int u = 0; u < 8; ++u) {
        ax = fmaf(wv[u], bf2f((unsigned short)(hv[u].x & 0xFFFF)), ax);
        ay = fmaf(wv[u], bf2f((unsigned short)(hv[u].x >> 16)), ay);
        az = fmaf(wv[u], bf2f((unsigned short)(hv[u].y & 0xFFFF)), az);
        aw = fmaf(wv[u], bf2f((unsigned short)(hv[u].y >> 16)), aw);
      }
    }
    for (int e = CAP; e < deg; ++e) {
      int s = srt[start + e];
      float v = as_[s] + adn;
      v = v > 0.f ? v : 0.2f * v;
      float w = __expf(v - m);
      if (act && g == 0) {
        uint2 hv = *(const uint2*)&hb[(size_t)s * DO + pidx * 4];
        ax = fmaf(w, bf2f((unsigned short)(hv.x & 0xFFFF)), ax);
        ay = fmaf(w, bf2f((unsigned short)(hv.x >> 16)), ay);
        az = fmaf(w, bf2f((unsigned short)(hv.y & 0xFFFF)), az);
        aw = fmaf(w, bf2f((unsigned short)(hv.y >> 16)), aw);
      }
    }

    float sx = 0.f, sy = 0.f, sz = 0.f, sw = 0.f;
    #pragma unroll
    for (int gg = 0; gg < GR; ++gg) {
      int src = pidx + gg * LR;
      sx += __shfl(ax, src, 64);
      sy += __shfl(ay, src, 64);
      sz += __shfl(az, src, 64);
      sw += __shfl(aw, src, 64);
    }

    if (lane < LR) {
      const int cb = pidx * 4;
      float4 rv = *(const float4*)&xRl[(size_t)node * DO + cb];
      float ox = fmaxf(sx * inv, 0.f) + rv.x;
      float oy = fmaxf(sy * inv, 0.f) + rv.y;
      float oz = fmaxf(sz * inv, 0.f) + rv.z;
      float ow = fmaxf(sw * inv, 0.f) + rv.w;
      if constexpr (NTn == 0) {
        *(float4*)&dout[(size_t)node * DO + cb] = make_float4(ox, oy, oz, ow);
      } else {
        uint32_t p0 = (uint32_t)f2bf(ox) | ((uint32_t)f2bf(oy) << 16);
        uint32_t p1 = (uint32_t)f2bf(oz) | ((uint32_t)f2bf(ow) << 16);
        *(uint2*)&xAl[row * PIT + cb] = make_uint2(p0, p1);
      }
    }
  }

  // ---- phase 2: next-layer GEMM on the 16-node tile ----
  if constexpr (NTn > 0) {
    constexpr int NHn = NTn / 2;
    constexpr int TPW = (NTn + 3) / 4;
    constexpr int DOn = NTn * 8;
    __syncthreads();
    const int fr = lane & 15;
    const int fq = lane >> 4;

    f4v acc[TPW];
    #pragma unroll
    for (int tt = 0; tt < TPW; ++tt) acc[tt] = (f4v)(0.f);

    #pragma unroll
    for (int ks = 0; ks < 3; ++ks) {    // K = 96 = 3 x 32
      s8v a = *(const s8v*)&xAl[fr * PIT + ks * 32 + fq * 8];
      #pragma unroll
      for (int tt = 0; tt < TPW; ++tt) {
        int t = wid * TPW + tt;
        if (t < NTn) {
          s8v b = *(const s8v*)&Wtn[(size_t)(t * 16 + fr) * 96 + ks * 32 + fq * 8];
          acc[tt] = __builtin_amdgcn_mfma_f32_16x16x32_bf16(a, b, acc[tt], 0, 0, 0);
        }
      }
    }

    float lps[4] = {0.f, 0.f, 0.f, 0.f}, lpd[4] = {0.f, 0.f, 0.f, 0.f};
    #pragma unroll
    for (int tt = 0; tt < TPW; ++tt) {
      int t = wid * TPW + tt;
      if (t < NTn) {
        int gcol = t * 16 + fr;
        if (t < NHn) {
          float avsv = nas[gcol], avdv = nad[gcol];
          #pragma unroll
          for (int r = 0; r < 4; ++r) {
            int grow = node0 + fq * 4 + r;
            hbn[(size_t)grow * DOn + gcol] = f2bf(acc[tt][r]);
            lps[r] = fmaf(acc[tt][r], avsv, lps[r]);
            lpd[r] = fmaf(acc[tt][r], avdv, lpd[r]);
          }
        } else {
          #pragma unroll
          for (int r = 0; r < 4; ++r) {
            int grow = node0 + fq * 4 + r;
            xRn[(size_t)grow * DOn + (gcol - DOn)] = acc[tt][r];
          }
        }
      }
    }

    #pragma unroll
    for (int r = 0; r < 4; ++r) {
      #pragma unroll
      for (int off = 1; off < 16; off <<= 1) {
        lps[r] += __shfl_xor(lps[r], off, 64);
        lpd[r] += __shfl_xor(lpd[r], off, 64);
      }
    }
    if (fr == 0) {
      #pragma unroll
      for (int r = 0; r < 4; ++r) {
        pps[wid][fq * 4 + r] = lps[r];
        ppd[wid][fq * 4 + r] = lpd[r];
      }
    }
    __syncthreads();
    if (threadIdx.x < 16) {
      int row = threadIdx.x;
      float ps = pps[0][row] + pps[1][row] + pps[2][row] + pps[3][row];
      float pd = ppd[0][row] + ppd[1][row] + ppd[2][row] + ppd[3][row];
      asbn[node0 + row] = ps;
      adbn[node0 + row] = pd;
      float ms = ps, md = pd;
      #pragma unroll
      for (int off = 1; off < 16; off <<= 1) {
        ms = fmaxf(ms, __shfl_xor(ms, off, 64));
        md = fmaxf(md, __shfl_xor(md, off, 64));
      }
      if (row == 0) { atomicMax(mkn + 0, fkey(ms)); atomicMax(mkn + 1, fkey(md)); }
    }
  }
}

// ---------------- launch ----------------

extern "C" void kernel_launch(void* const* d_in, const int* in_sizes, int n_in,
                              void* d_out, int out_size, void* d_ws, size_t ws_size,
                              hipStream_t stream) {
  const int N = NNODES;
  const float* x0 = (const float*)d_in[0];
  const int*   ei = (const int*)d_in[1];
  const int E = in_sizes[1] / 2;

  const float* W0 = (const float*)d_in[2];
  const float* a0s = (const float*)d_in[3];
  const float* a0d = (const float*)d_in[4];
  const float* R0 = (const float*)d_in[5];
  const float* W1 = (const float*)d_in[6];
  const float* a1s = (const float*)d_in[7];
  const float* a1d = (const float*)d_in[8];
  const float* R1 = (const float*)d_in[9];
  const float* W2 = (const float*)d_in[10];
  const float* a2s = (const float*)d_in[11];
  const float* a2d = (const float*)d_in[12];
  const float* R2 = (const float*)d_in[13];
  const float* W3 = (const float*)d_in[14];
  const float* a3s = (const float*)d_in[15];
  const float* a3d = (const float*)d_in[16];
  const float* R3 = (const float*)d_in[17];

  char* p = (char*)d_ws;
  auto alloc = [&](size_t bytes) {
    char* r = p;
    p += (bytes + 255) & ~(size_t)255;
    return r;
  };
  int*   deg    = (int*)alloc((size_t)N * 4);
  int*   offs   = (int*)alloc((size_t)(N + 1) * 4);
  int*   blksum = (int*)alloc(64 * 4);
  unsigned* mk  = (unsigned*)alloc(8 * 4);
  int*   rank   = (int*)alloc((size_t)E * 4);
  int*   srt    = (int*)alloc((size_t)(E + N) * 4);
  unsigned short* hb0 = (unsigned short*)alloc((size_t)N * 96 * 2);
  unsigned short* hb1 = (unsigned short*)alloc((size_t)N * 96 * 2);
  float* xR0    = (float*)alloc((size_t)N * 96 * 4);
  float* xR1    = (float*)alloc((size_t)N * 96 * 4);
  float* asb0   = (float*)alloc((size_t)N * 4);
  float* adb0   = (float*)alloc((size_t)N * 4);
  float* asb1   = (float*)alloc((size_t)N * 4);
  float* adb1   = (float*)alloc((size_t)N * 4);
  unsigned short* Wt0 = (unsigned short*)alloc((size_t)192 * 256 * 2);
  unsigned short* Wt1 = (unsigned short*)alloc((size_t)192 * 96 * 2);
  unsigned short* Wt2 = (unsigned short*)alloc((size_t)192 * 96 * 2);
  unsigned short* Wt3 = (unsigned short*)alloc((size_t)96 * 96 * 2);

  const int NB = (N + 2047) / 2048;

  k_deg_init<<<(N + 255) / 256, 256, 0, stream>>>(deg, mk, N);
  k_deg_count<<<(E + 255) / 256, 256, 0, stream>>>(ei, deg, rank, E);
  k_scan1<<<NB, 256, 0, stream>>>(deg, offs, blksum, N);
  k_scan2<<<1, 64, 0, stream>>>(blksum, NB);
  k_scan3<<<(N + 255) / 256, 256, 0, stream>>>(offs, blksum, N);
  k_selfloop<<<(N + 255) / 256, 256, 0, stream>>>(offs, srt, N);
  k_scatter<<<(E + 255) / 256, 256, 0, stream>>>(ei, offs, rank, srt, E);

  k_wt_all<<<(95232 + 255) / 256, 256, 0, stream>>>(W0, R0, W1, R1, W2, R2, W3, R3,
                                                    Wt0, Wt1, Wt2, Wt3);

  const int GB = (N + 63) / 64;
  const int GA = N / 16;  // 3125

  // layer 0 GEMM: x0 (fp32, K=256) -> hb0, xR0, asb0, adb0, mk[0:2]
  gemm_mfma<256, 12><<<GB, 256, 0, stream>>>(x0, Wt0, a0s, a0d, hb0, xR0,
                                             asb0, adb0, mk);

  // agg0 (+GEMM1): reads layer-0 tensors, writes layer-1 tensors
  k_agg_fused<96, 12><<<GA, 256, 0, stream>>>(hb0, xR0, asb0, adb0, srt, offs, mk,
                                              Wt1, a1s, a1d, hb1, xR1, asb1, adb1,
                                              mk + 2, nullptr);
  // agg1 (+GEMM2)
  k_agg_fused<96, 12><<<GA, 256, 0, stream>>>(hb1, xR1, asb1, adb1, srt, offs, mk + 2,
                                              Wt2, a2s, a2d, hb0, xR0, asb0, adb0,
                                              mk + 4, nullptr);
  // agg2 (+GEMM3, next DOW=96 -> NTn=6)
  k_agg_fused<96, 6><<<GA, 256, 0, stream>>>(hb0, xR0, asb0, adb0, srt, offs, mk + 4,
                                             Wt3, a3s, a3d, hb1, xR1, asb1, adb1,
                                             mk + 6, nullptr);
  // agg3 final (DO=48) -> d_out
  k_agg_fused<48, 0><<<GA, 256, 0, stream>>>(hb1, xR1, asb1, adb1, srt, offs, mk + 6,
                                             nullptr, nullptr, nullptr, nullptr,
                                             nullptr, nullptr, nullptr, nullptr,
                                             (float*)d_out);
}

// Round 13
// 326.816 us; speedup vs baseline: 1.3745x; 1.3745x over previous
//
#include <hip/hip_runtime.h>
#include <hip/hip_bf16.h>
#include <cstdint>
#include <cstddef>

#define NNODES 50000

using s8v = __attribute__((ext_vector_type(8))) short;
using f4v = __attribute__((ext_vector_type(4))) float;

__device__ __forceinline__ unsigned short f2bf(float f) {
  union { float f; uint32_t u; } x; x.f = f;
  uint32_t r = x.u + 0x7FFF + ((x.u >> 16) & 1);  // RNE
  return (unsigned short)(r >> 16);
}
__device__ __forceinline__ float bf2f(unsigned short b) {
  union { uint32_t u; float f; } x; x.u = ((uint32_t)b) << 16;
  return x.f;
}
__device__ __forceinline__ unsigned fkey(float f) {
  unsigned u = __float_as_uint(f);
  return u ^ (((int)u >> 31) | 0x80000000u);
}
__device__ __forceinline__ float fdec(unsigned k) {
  return (k & 0x80000000u) ? __uint_as_float(k ^ 0x80000000u)
                           : __uint_as_float(~k);
}

// ---------------- CSR build ----------------

__global__ void k_deg_init(int* __restrict__ deg, unsigned* __restrict__ mk, int n) {
  int i = blockIdx.x * 256 + threadIdx.x;
  if (i < n) deg[i] = 1;  // self-loop occupies slot 0
  if (i < 8) mk[i] = 0;
}

__global__ void k_deg_count(const int* __restrict__ ei, int* __restrict__ deg,
                            int* __restrict__ rank, int E) {
  int e = blockIdx.x * 256 + threadIdx.x;
  if (e < E) rank[e] = atomicAdd(&deg[ei[E + e]], 1);
}

__global__ __launch_bounds__(256) void k_scan1(const int* __restrict__ deg,
                                               int* __restrict__ offs,
                                               int* __restrict__ blksum, int n) {
  __shared__ int part[256];
  const int tid = threadIdx.x;
  const int base = blockIdx.x * 2048 + tid * 8;
  int v[8]; int s = 0;
  #pragma unroll
  for (int u = 0; u < 8; ++u) {
    int i = base + u;
    v[u] = (i < n) ? deg[i] : 0;
    s += v[u];
  }
  part[tid] = s;
  __syncthreads();
  for (int off = 1; off < 256; off <<= 1) {
    int t = (tid >= off) ? part[tid - off] : 0;
    __syncthreads();
    part[tid] += t;
    __syncthreads();
  }
  int run = (tid == 0) ? 0 : part[tid - 1];
  #pragma unroll
  for (int u = 0; u < 8; ++u) {
    int i = base + u;
    run += v[u];
    if (i < n) offs[i + 1] = run;
  }
  if (tid == 255) blksum[blockIdx.x] = part[255];
}

__global__ void k_scan2(int* __restrict__ blksum, int nb) {
  int t = threadIdx.x;
  int v = (t < nb) ? blksum[t] : 0;
  for (int off = 1; off < 64; off <<= 1) {
    int o = __shfl_up(v, off, 64);
    if (t >= off) v += o;
  }
  if (t < nb) blksum[t] = v;
}

__global__ void k_scan3(int* __restrict__ offs, const int* __restrict__ blksum, int n) {
  int i = blockIdx.x * 256 + threadIdx.x;
  if (i < n) {
    int b = i >> 11;
    if (b > 0) offs[i + 1] += blksum[b - 1];
  }
  if (i == 0) offs[0] = 0;
}

__global__ void k_selfloop(const int* __restrict__ offs, int* __restrict__ srt, int n) {
  int i = blockIdx.x * 256 + threadIdx.x;
  if (i < n) srt[offs[i]] = i;
}

__global__ void k_scatter(const int* __restrict__ ei, const int* __restrict__ offs,
                          const int* __restrict__ rank, int* __restrict__ srt, int E) {
  int e = blockIdx.x * 256 + threadIdx.x;
  if (e < E) {
    int s = ei[e], d = ei[E + e];
    srt[offs[d] + rank[e]] = s;
  }
}

// ---------------- weight pre-transpose + bf16 convert (all 4 layers) ----------------

__global__ void k_wt_all(const float* __restrict__ W0, const float* __restrict__ R0,
                         const float* __restrict__ W1, const float* __restrict__ R1,
                         const float* __restrict__ W2, const float* __restrict__ R2,
                         const float* __restrict__ W3, const float* __restrict__ R3,
                         unsigned short* __restrict__ Wt0, unsigned short* __restrict__ Wt1,
                         unsigned short* __restrict__ Wt2, unsigned short* __restrict__ Wt3) {
  int idx = blockIdx.x * 256 + threadIdx.x;
  const float *W, *R; unsigned short* Wt; int K, DO, l;
  if (idx < 49152)      { l = idx;          W = W0; R = R0; Wt = Wt0; K = 256; DO = 96; }
  else if (idx < 67584) { l = idx - 49152;  W = W1; R = R1; Wt = Wt1; K = 96;  DO = 96; }
  else if (idx < 86016) { l = idx - 67584;  W = W2; R = R2; Wt = Wt2; K = 96;  DO = 96; }
  else if (idx < 95232) { l = idx - 86016;  W = W3; R = R3; Wt = Wt3; K = 96;  DO = 48; }
  else return;
  int n = l / K, k = l % K;
  float v = (n < DO) ? W[(size_t)k * DO + n] : R[(size_t)k * DO + (n - DO)];
  Wt[l] = f2bf(v);
}

// ---------------- MFMA GEMM + fused alpha dots + global max bound ----------------
// BM=64, 4 waves each own a 16-row band; register-prefetch double buffering.
// ABF16: A matrix already bf16 -> staging is a pure copy.

template<int KDIM, int NT, bool ABF16>   // NT = DOW/16
__global__ __launch_bounds__(256) void gemm_mfma(
    const void* __restrict__ xin, const unsigned short* __restrict__ Wt,
    const float* __restrict__ a_s, const float* __restrict__ a_d,
    unsigned short* __restrict__ hb, float* __restrict__ xR,
    float* __restrict__ asb, float* __restrict__ adb,
    unsigned* __restrict__ mk) {
  constexpr int DOW = NT * 16;
  constexpr int DO  = DOW / 2;
  constexpr int NH  = NT / 2;
  constexpr int BM  = 64;
  constexpr int AP  = 40;
  constexpr int NBS = (DOW * 4 + 255) / 256;
  __shared__ __align__(16) unsigned short Al[BM * AP];
  __shared__ __align__(16) unsigned short Bl[DOW * AP];
  __shared__ float wmax[4][2];

  const int tid  = threadIdx.x;
  const int wave = tid >> 6;
  const int lane = tid & 63;
  const int row0 = blockIdx.x * BM;

  const int ar = tid >> 2, ako = (tid & 3) * 8;
  const int agr = row0 + ar;

  f4v acc[NT];
  #pragma unroll
  for (int t = 0; t < NT; ++t) acc[t] = (f4v)(0.f);

  const int fr = lane & 15;
  const int fq = lane >> 4;

  auto loadA = [&](int k0) -> s8v {
    s8v out = (s8v)(0);
    if (agr < NNODES) {
      if constexpr (ABF16) {
        out = *(const s8v*)&((const unsigned short*)xin)[(size_t)agr * KDIM + k0 + ako];
      } else {
        const float* xp = &((const float*)xin)[(size_t)agr * KDIM + k0 + ako];
        float4 v0 = *(const float4*)(xp);
        float4 v1 = *(const float4*)(xp + 4);
        out[0] = (short)f2bf(v0.x); out[1] = (short)f2bf(v0.y);
        out[2] = (short)f2bf(v0.z); out[3] = (short)f2bf(v0.w);
        out[4] = (short)f2bf(v1.x); out[5] = (short)f2bf(v1.y);
        out[6] = (short)f2bf(v1.z); out[7] = (short)f2bf(v1.w);
      }
    }
    return out;
  };

  // prologue: stage tile 0
  {
    s8v aC = loadA(0);
    s8v bC[NBS];
    #pragma unroll
    for (int i = 0; i < NBS; ++i) {
      int s = tid + i * 256;
      if (s < DOW * 4) {
        int n = s >> 2, kq = (s & 3) * 8;
        bC[i] = *(const s8v*)&Wt[(size_t)n * KDIM + kq];
      }
    }
    *(s8v*)&Al[ar * AP + ako] = aC;
    #pragma unroll
    for (int i = 0; i < NBS; ++i) {
      int s = tid + i * 256;
      if (s < DOW * 4) {
        int n = s >> 2, kq = (s & 3) * 8;
        *(s8v*)&Bl[n * AP + kq] = bC[i];
      }
    }
  }

  for (int k0 = 32; k0 <= KDIM; k0 += 32) {
    __syncthreads();
    const bool more = (k0 < KDIM);
    s8v aN; s8v bN[NBS];
    if (more) {
      aN = loadA(k0);
      #pragma unroll
      for (int i = 0; i < NBS; ++i) {
        int s = tid + i * 256;
        if (s < DOW * 4) {
          int n = s >> 2, kq = (s & 3) * 8;
          bN[i] = *(const s8v*)&Wt[(size_t)n * KDIM + k0 + kq];
        }
      }
    }
    s8v a = *(const s8v*)&Al[(wave * 16 + fr) * AP + fq * 8];
    #pragma unroll
    for (int t = 0; t < NT; ++t) {
      s8v b = *(const s8v*)&Bl[(t * 16 + fr) * AP + fq * 8];
      acc[t] = __builtin_amdgcn_mfma_f32_16x16x32_bf16(a, b, acc[t], 0, 0, 0);
    }
    if (more) {
      __syncthreads();
      *(s8v*)&Al[ar * AP + ako] = aN;
      #pragma unroll
      for (int i = 0; i < NBS; ++i) {
        int s = tid + i * 256;
        if (s < DOW * 4) {
          int n = s >> 2, kq = (s & 3) * 8;
          *(s8v*)&Bl[n * AP + kq] = bN[i];
        }
      }
    }
  }

  // C write: D col = lane&15, row = (lane>>4)*4 + reg
  #pragma unroll
  for (int t = 0; t < NT; ++t) {
    int gcol = t * 16 + fr;
    #pragma unroll
    for (int r = 0; r < 4; ++r) {
      int grow = row0 + wave * 16 + fq * 4 + r;
      if (grow >= NNODES) continue;
      if (t < NH) hb[(size_t)grow * DO + gcol] = f2bf(acc[t][r]);
      else        xR[(size_t)grow * DO + (gcol - DO)] = acc[t][r];
    }
  }

  // fused alpha dots + running max for global softmax bound
  float avs[NH], avd[NH];
  #pragma unroll
  for (int t = 0; t < NH; ++t) {
    avs[t] = a_s[t * 16 + fr];
    avd[t] = a_d[t * 16 + fr];
  }
  float lms = -INFINITY, lmd = -INFINITY;
  #pragma unroll
  for (int r = 0; r < 4; ++r) {
    float ps = 0.f, pd = 0.f;
    #pragma unroll
    for (int t = 0; t < NH; ++t) {
      ps = fmaf(acc[t][r], avs[t], ps);
      pd = fmaf(acc[t][r], avd[t], pd);
    }
    #pragma unroll
    for (int off = 1; off < 16; off <<= 1) {
      ps += __shfl_xor(ps, off, 64);
      pd += __shfl_xor(pd, off, 64);
    }
    int grow = row0 + wave * 16 + fq * 4 + r;
    if (fr == 0 && grow < NNODES) { asb[grow] = ps; adb[grow] = pd; }
    lms = fmaxf(lms, ps); lmd = fmaxf(lmd, pd);
  }
  lms = fmaxf(lms, __shfl_xor(lms, 16, 64));
  lms = fmaxf(lms, __shfl_xor(lms, 32, 64));
  lmd = fmaxf(lmd, __shfl_xor(lmd, 16, 64));
  lmd = fmaxf(lmd, __shfl_xor(lmd, 32, 64));
  if (lane == 0) { wmax[wave][0] = lms; wmax[wave][1] = lmd; }
  __syncthreads();
  if (tid == 0) {
    float a = fmaxf(fmaxf(wmax[0][0], wmax[1][0]), fmaxf(wmax[2][0], wmax[3][0]));
    float b = fmaxf(fmaxf(wmax[0][1], wmax[1][1]), fmaxf(wmax[2][1], wmax[3][1]));
    atomicMax(mk + 0, fkey(a));
    atomicMax(mk + 1, fkey(b));
  }
}

// ---------------- fused softmax + aggregate + relu + residual ----------------
// Single pass, global-bound softmax. Gather: GR rows per instruction
// (uint2 = 4 bf16/lane; LR = DO/4 lanes per row; GR = 48/LR).
// OUTBF: write bf16 activation (inter-layer) vs fp32 (final output).

template<int DO, bool OUTBF>
__global__ __launch_bounds__(256) void k_aggregate(
    const unsigned short* __restrict__ hb, const float* __restrict__ xR,
    const float* __restrict__ as_, const float* __restrict__ ad_,
    const int* __restrict__ srt, const int* __restrict__ offs,
    const unsigned* __restrict__ mk, void* __restrict__ xout, int n) {
  constexpr int CAP = 256;
  constexpr int LR  = DO / 4;    // lanes per row (24 or 12)
  constexpr int GR  = 48 / LR;   // rows per gather instruction (2 or 4)
  __shared__ float wbuf[4][CAP];
  __shared__ int   sbuf[4][CAP];
  const int lane = threadIdx.x & 63;
  const int wid  = threadIdx.x >> 6;
  const int node = blockIdx.x * 4 + wid;
  if (node >= n) return;
  const int start = offs[node];
  const int deg   = offs[node + 1] - start;
  const float adn = ad_[node];
  const float m = fmaxf(0.f, fdec(mk[0]) + fdec(mk[1]));

  // phase 1: w = exp(leaky - m), cache (w, s), sum
  float ssum = 0.f;
  for (int idx = lane; idx < deg; idx += 64) {
    int s = srt[start + idx];
    float v = as_[s] + adn;
    v = v > 0.f ? v : 0.2f * v;
    float w = __expf(v - m);
    if (idx < CAP) { wbuf[wid][idx] = w; sbuf[wid][idx] = s; }
    ssum += w;
  }
  #pragma unroll
  for (int off = 32; off; off >>= 1) ssum += __shfl_xor(ssum, off, 64);
  const float inv = 1.f / fmaxf(ssum, 1e-30f);

  // phase 2: gather, GR edges per instruction, 8-deep unroll
  const int g    = lane / LR;
  const int pidx = lane % LR;
  const bool act = lane < 48;
  const int dcap = min(deg, CAP);
  float ax = 0.f, ay = 0.f, az = 0.f, aw = 0.f;
  for (int base = 0; base < dcap; base += 8 * GR) {
    float wv[8]; int sv[8];
    #pragma unroll
    for (int u = 0; u < 8; ++u) {
      int e = base + u * GR + g;
      bool ok = act && (e < dcap);
      sv[u] = sbuf[wid][ok ? e : 0];
      wv[u] = ok ? wbuf[wid][e] : 0.f;
    }
    uint2 hv[8];
    #pragma unroll
    for (int u = 0; u < 8; ++u)
      hv[u] = act ? *(const uint2*)&hb[(size_t)sv[u] * DO + pidx * 4]
                  : make_uint2(0u, 0u);
    #pragma unroll
    for (int u = 0; u < 8; ++u) {
      ax = fmaf(wv[u], bf2f((unsigned short)(hv[u].x & 0xFFFF)), ax);
      ay = fmaf(wv[u], bf2f((unsigned short)(hv[u].x >> 16)), ay);
      az = fmaf(wv[u], bf2f((unsigned short)(hv[u].y & 0xFFFF)), az);
      aw = fmaf(wv[u], bf2f((unsigned short)(hv[u].y >> 16)), aw);
    }
  }
  // rare overflow (deg > CAP): group 0 only
  for (int e = CAP; e < deg; ++e) {
    int s = srt[start + e];
    float v = as_[s] + adn;
    v = v > 0.f ? v : 0.2f * v;
    float w = __expf(v - m);
    if (act && g == 0) {
      uint2 hv = *(const uint2*)&hb[(size_t)s * DO + pidx * 4];
      ax = fmaf(w, bf2f((unsigned short)(hv.x & 0xFFFF)), ax);
      ay = fmaf(w, bf2f((unsigned short)(hv.x >> 16)), ay);
      az = fmaf(w, bf2f((unsigned short)(hv.y & 0xFFFF)), az);
      aw = fmaf(w, bf2f((unsigned short)(hv.y >> 16)), aw);
    }
  }

  // combine groups
  float sx = 0.f, sy = 0.f, sz = 0.f, sw = 0.f;
  #pragma unroll
  for (int gg = 0; gg < GR; ++gg) {
    int src = pidx + gg * LR;
    sx += __shfl(ax, src, 64);
    sy += __shfl(ay, src, 64);
    sz += __shfl(az, src, 64);
    sw += __shfl(aw, src, 64);
  }

  if (lane < LR) {
    const size_t b = (size_t)node * DO + pidx * 4;
    float4 rv = *(const float4*)&xR[b];
    float ox = fmaxf(sx * inv, 0.f) + rv.x;
    float oy = fmaxf(sy * inv, 0.f) + rv.y;
    float oz = fmaxf(sz * inv, 0.f) + rv.z;
    float ow = fmaxf(sw * inv, 0.f) + rv.w;
    if constexpr (OUTBF) {
      uint32_t p0 = (uint32_t)f2bf(ox) | ((uint32_t)f2bf(oy) << 16);
      uint32_t p1 = (uint32_t)f2bf(oz) | ((uint32_t)f2bf(ow) << 16);
      *(uint2*)&((unsigned short*)xout)[b] = make_uint2(p0, p1);
    } else {
      *(float4*)&((float*)xout)[b] = make_float4(ox, oy, oz, ow);
    }
  }
}

// ---------------- launch ----------------

extern "C" void kernel_launch(void* const* d_in, const int* in_sizes, int n_in,
                              void* d_out, int out_size, void* d_ws, size_t ws_size,
                              hipStream_t stream) {
  const int N = NNODES;
  const float* x0 = (const float*)d_in[0];
  const int*   ei = (const int*)d_in[1];
  const int E = in_sizes[1] / 2;

  const float* W0 = (const float*)d_in[2];
  const float* a0s = (const float*)d_in[3];
  const float* a0d = (const float*)d_in[4];
  const float* R0 = (const float*)d_in[5];
  const float* W1 = (const float*)d_in[6];
  const float* a1s = (const float*)d_in[7];
  const float* a1d = (const float*)d_in[8];
  const float* R1 = (const float*)d_in[9];
  const float* W2 = (const float*)d_in[10];
  const float* a2s = (const float*)d_in[11];
  const float* a2d = (const float*)d_in[12];
  const float* R2 = (const float*)d_in[13];
  const float* W3 = (const float*)d_in[14];
  const float* a3s = (const float*)d_in[15];
  const float* a3d = (const float*)d_in[16];
  const float* R3 = (const float*)d_in[17];

  char* p = (char*)d_ws;
  auto alloc = [&](size_t bytes) {
    char* r = p;
    p += (bytes + 255) & ~(size_t)255;
    return r;
  };
  int*   deg    = (int*)alloc((size_t)N * 4);
  int*   offs   = (int*)alloc((size_t)(N + 1) * 4);
  int*   blksum = (int*)alloc(64 * 4);
  unsigned* mk  = (unsigned*)alloc(8 * 4);
  int*   rank   = (int*)alloc((size_t)E * 4);
  int*   srt    = (int*)alloc((size_t)(E + N) * 4);
  unsigned short* hb  = (unsigned short*)alloc((size_t)N * 96 * 2);
  unsigned short* xAb = (unsigned short*)alloc((size_t)N * 96 * 2);
  float* xR     = (float*)alloc((size_t)N * 96 * 4);
  float* asb    = (float*)alloc((size_t)N * 4);
  float* adb    = (float*)alloc((size_t)N * 4);
  unsigned short* Wt0 = (unsigned short*)alloc((size_t)192 * 256 * 2);
  unsigned short* Wt1 = (unsigned short*)alloc((size_t)192 * 96 * 2);
  unsigned short* Wt2 = (unsigned short*)alloc((size_t)192 * 96 * 2);
  unsigned short* Wt3 = (unsigned short*)alloc((size_t)96 * 96 * 2);

  const int NB = (N + 2047) / 2048;

  k_deg_init<<<(N + 255) / 256, 256, 0, stream>>>(deg, mk, N);
  k_deg_count<<<(E + 255) / 256, 256, 0, stream>>>(ei, deg, rank, E);
  k_scan1<<<NB, 256, 0, stream>>>(deg, offs, blksum, N);
  k_scan2<<<1, 64, 0, stream>>>(blksum, NB);
  k_scan3<<<(N + 255) / 256, 256, 0, stream>>>(offs, blksum, N);
  k_selfloop<<<(N + 255) / 256, 256, 0, stream>>>(offs, srt, N);
  k_scatter<<<(E + 255) / 256, 256, 0, stream>>>(ei, offs, rank, srt, E);

  k_wt_all<<<(95232 + 255) / 256, 256, 0, stream>>>(W0, R0, W1, R1, W2, R2, W3, R3,
                                                    Wt0, Wt1, Wt2, Wt3);

  const int GB = (N + 63) / 64;
  const int GA = (N + 3) / 4;

  // layer 0: K=256, DO=96 (fp32 A)
  gemm_mfma<256, 12, false><<<GB, 256, 0, stream>>>(x0, Wt0, a0s, a0d, hb, xR,
                                                    asb, adb, mk);
  k_aggregate<96, true><<<GA, 256, 0, stream>>>(hb, xR, asb, adb, srt, offs, mk,
                                                xAb, N);

  // layer 1 (bf16 A)
  gemm_mfma<96, 12, true><<<GB, 256, 0, stream>>>(xAb, Wt1, a1s, a1d, hb, xR,
                                                  asb, adb, mk + 2);
  k_aggregate<96, true><<<GA, 256, 0, stream>>>(hb, xR, asb, adb, srt, offs, mk + 2,
                                                xAb, N);

  // layer 2 (bf16 A)
  gemm_mfma<96, 12, true><<<GB, 256, 0, stream>>>(xAb, Wt2, a2s, a2d, hb, xR,
                                                  asb, adb, mk + 4);
  k_aggregate<96, true><<<GA, 256, 0, stream>>>(hb, xR, asb, adb, srt, offs, mk + 4,
                                                xAb, N);

  // layer 3: K=96, DO=48 (bf16 A) -> d_out fp32
  gemm_mfma<96, 6, true><<<GB, 256, 0, stream>>>(xAb, Wt3, a3s, a3d, hb, xR,
                                                 asb, adb, mk + 6);
  k_aggregate<48, false><<<GA, 256, 0, stream>>>(hb, xR, asb, adb, srt, offs, mk + 6,
                                                 d_out, N);
}